// Round 11
// baseline (129.544 us; speedup 1.0000x reference)
//
#include <hip/hip_runtime.h>

#define N_NODES 100000
#define N_EDGES 1000000
#define D 64

#define NFINE 782             // fine bin = dst >> 7 (128 nodes each)
#define CAP2 1536             // per-bin cap: mean 1280 + ~7 sigma
#define CHUNK 4096            // edges per build block (R2/R5-measured best)
#define EDGE_BLOCKS 245       // ceil(1e6 / 4096)
#define CONV_ITEMS 1600000    // N*D/4 float4s
#define CONV_STRIDE (EDGE_BLOCKS * 1024)
#define CONS_BLOCKS 3128      // 782 bins x 4 quarters, 32 nodes / 256-thr block
#define STR 132               // As row stride in u16
#define SCAP 512              // sorted_s slots per 32-node quarter

typedef unsigned short u16;
typedef unsigned int u32;
typedef unsigned char u8;
using bf16x8 = __attribute__((ext_vector_type(8))) short;
using f32x4  = __attribute__((ext_vector_type(4))) float;

__device__ __forceinline__ u16 f2bf(float f) {   // RNE float->bf16
    u32 u = __float_as_uint(f);
    return (u16)((u + 0x7FFF + ((u >> 16) & 1)) >> 16);
}
__device__ __forceinline__ float bf2f(u16 v) {
    return __uint_as_float(((u32)v) << 16);
}

// ===========================================================================
// build5: R10 verbatim — build + conv fused (fusion isolated at -1.4us),
// plain cur2 (CSTR padding isolated at +5.4us, reverted in R9), LDS
// counting sort CHUNK 4096. Block 0 pre-converts weights into Wb.
// cur2 zeroed by hipMemsetAsync. Packed pair = src(17b) | dst_local7<<17.
// ===========================================================================
__global__ __launch_bounds__(1024) void build5_kernel(
    const float* __restrict__ x, u16* __restrict__ xb,
    const float* __restrict__ Wl, const float* __restrict__ Wr,
    u16* __restrict__ Wb,
    const int* __restrict__ ei, int* __restrict__ cur2,
    u32* __restrict__ pairs2) {
    __shared__ u32 sorted[CHUNK];    // 16 KB
    __shared__ u16 binof[CHUNK];     //  8 KB
    __shared__ int hist[NFINE];
    __shared__ int off_l[NFINE];
    __shared__ int cur_l[NFINE];
    __shared__ int base_g[NFINE];
    __shared__ int wsum[16];

    int b = blockIdx.x;
    int t = threadIdx.x;
    int ln = t & 63;
    int wv = t >> 6;

    // int64/int32 detect: indices < 2^17 -> int64 odd u32 words all zero
    const u32* uu = (const u32*)ei;
    int f = 1;
    #pragma unroll
    for (int i = 1; i < 16; i += 2)
        if (uu[i] != 0u) f = 0;

    if (t < NFINE) hist[t] = 0;
    __syncthreads();

    int e0 = b * CHUNK;
    int e1 = min(e0 + CHUNK, N_EDGES);
    int ne = e1 - e0;

    // ---- edge loads (coalesced uint2 for int64 path) ----
    const uint2* e64 = (const uint2*)ei;
    int srcv[4], dstv[4];
    #pragma unroll
    for (int i = 0; i < 4; i++) {
        int ee = e0 + t + i * 1024;
        bool ok = ee < e1;
        if (f) {
            uint2 sv = ok ? e64[ee] : make_uint2(0u, 0u);
            uint2 dv = ok ? e64[N_EDGES + ee] : make_uint2(0u, 0u);
            srcv[i] = (int)sv.x;
            dstv[i] = ok ? (int)dv.x : -1;
        } else {
            srcv[i] = ok ? ei[ee] : 0;
            dstv[i] = ok ? ei[N_EDGES + ee] : -1;
        }
    }

    // ---- issue conv-slice loads early (7 float4/thread, grid-stride) ----
    float4 cf[7];
    const float4* x4 = (const float4*)x;
    #pragma unroll
    for (int j = 0; j < 7; j++) {
        int i = b * 1024 + t + j * CONV_STRIDE;
        cf[j] = (i < CONV_ITEMS) ? x4[i] : make_float4(0.f, 0.f, 0.f, 0.f);
    }

    // ---- block 0: pre-convert weights into Wb bf16 [64][128] ----
    if (b == 0 && t < 256) {
        int o = t >> 2;
        int k0 = (t & 3) * 32;
        const float4* wlf = (const float4*)Wl;
        const float4* wrf = (const float4*)Wr;
        #pragma unroll
        for (int j = 0; j < 8; j++) {
            int k = k0 + j * 4;
            float4 v = (k < 64) ? wlf[(o * 64 + k) >> 2]
                                : wrf[(o * 64 + k - 64) >> 2];
            *(ushort4*)&Wb[o * 128 + k] =
                make_ushort4(f2bf(v.x), f2bf(v.y), f2bf(v.z), f2bf(v.w));
        }
    }

    // ---- histogram ----
    #pragma unroll
    for (int i = 0; i < 4; i++)
        if (dstv[i] >= 0) atomicAdd(&hist[dstv[i] >> 7], 1);
    __syncthreads();

    // ---- two-level wave scan over 782 bins ----
    int h = (t < NFINE) ? hist[t] : 0;
    int inc = h;
    #pragma unroll
    for (int o = 1; o < 64; o <<= 1) {
        int v = __shfl_up(inc, o);
        if (ln >= o) inc += v;
    }
    if (ln == 63) wsum[wv] = inc;
    __syncthreads();
    if (t < 16) {
        int w = wsum[t];
        int winc = w;
        #pragma unroll
        for (int o = 1; o < 16; o <<= 1) {
            int v = __shfl_up(winc, o);
            if (t >= o) winc += v;
        }
        wsum[t] = winc - w;          // exclusive wave offset
    }
    __syncthreads();

    // ---- reservation (plain cur2 — same-line L2 atomic batching helps) ----
    if (t < NFINE) {
        int ex = inc - h + wsum[wv]; // exclusive prefix
        off_l[t] = ex;
        cur_l[t] = ex;
        base_g[t] = h ? atomicAdd(&cur2[t], h) : 0;
    }

    // ---- conv convert + store (overlaps reservation atomic latency) ----
    #pragma unroll
    for (int j = 0; j < 7; j++) {
        int i = b * 1024 + t + j * CONV_STRIDE;
        if (i < CONV_ITEMS) {
            float4 v = cf[j];
            ((ushort4*)xb)[i] =
                make_ushort4(f2bf(v.x), f2bf(v.y), f2bf(v.z), f2bf(v.w));
        }
    }
    __syncthreads();

    // ---- placement: counting-sort into LDS ----
    #pragma unroll
    for (int i = 0; i < 4; i++) {
        if (dstv[i] >= 0) {
            int fine = dstv[i] >> 7;
            int slot = atomicAdd(&cur_l[fine], 1);
            sorted[slot] = (u32)srcv[i] | ((u32)(dstv[i] & 127) << 17);
            binof[slot] = (u16)fine;
        }
    }
    __syncthreads();

    // ---- linear coalesced flush ----
    for (int i = t; i < ne; i += 1024) {
        int fine = binof[i];
        int pos = base_g[fine] + (i - off_l[fine]);
        if (pos < CAP2)
            pairs2[(size_t)fine * CAP2 + pos] = sorted[i];
    }
}

// ===========================================================================
// cons8: R10's cons7b + ONE isolated change: DEGREE-SORTED node->wave
// assignment. Gather runs each 8-node group to the group max degree;
// unsorted E[max of 8 Poisson(10)] ~ 15-16 vs mean 10 -> ~35% masked
// waste. Rank nodes by degree (32-step shfl compare on wave 0, once per
// block, ~zero cost), wave w gathers ranks [8w,8w+8) -> similar degrees
// -> Sum(wave maxd) drops ~25-30%. R3 tried this bundled with an 8-buffer
// pipeline that spilled; isolated here: no new hot-loop live state
// (nl comes from one broadcast LDS byte read). Everything else verbatim.
// MFMA epilogue: C/D col=lane&15, row=quad*4+reg (m89/m91).
// ===========================================================================
__global__ __launch_bounds__(256, 8) void cons8_kernel(
    const u16* __restrict__ xb, const u16* __restrict__ Wb,
    const float* __restrict__ bl,
    const int* __restrict__ cur2, const u32* __restrict__ pairs2,
    float* __restrict__ out) {
    __shared__ u16 As[32 * STR];     //  8448 B
    __shared__ int sorted_s[SCAP];   //  2048 B
    __shared__ int deg_l[32];
    __shared__ int off_l[32];
    __shared__ int cur_l[32];
    __shared__ u8  perm_s[32];

    int tid = threadIdx.x;
    int bin = blockIdx.x >> 2;
    int quarter = blockIdx.x & 3;
    int nbase = bin * 128 + quarter * 32;
    if (nbase >= N_NODES) return;    // phantom quarters of last bin

    int lane = tid & 63;
    int wv = tid >> 6;

    // ---- issue pair loads first (long-latency, hide under init) ----
    int cnt = min(cur2[bin], CAP2);
    const u32* pb = &pairs2[(size_t)bin * CAP2];
    u32 ve[6];                       // CAP2/256 == 6
    #pragma unroll
    for (int i = 0; i < 6; i++) {
        int e = tid + i * 256;
        ve[i] = (e < cnt) ? pb[e] : 0xFFFFFFFFu;   // sentinel fails quarter test
    }

    if (tid < 32) { deg_l[tid] = 0; cur_l[tid] = 0; }
    if (tid == 0) sorted_s[0] = 0;   // safe slot for d==0 lanes
    __syncthreads();

    // ---- histogram over this quarter's 32 local nodes ----
    #pragma unroll
    for (int i = 0; i < 6; i++) {
        u32 v = ve[i];
        if ((int)(v >> 22) == quarter) atomicAdd(&deg_l[(v >> 17) & 31], 1);
    }
    __syncthreads();

    // ---- scan + degree-rank of 32 nodes (lanes 0..31 of wave 0) ----
    if (tid < 32) {
        int dd = deg_l[tid];
        int inc = dd;
        #pragma unroll
        for (int o = 1; o < 32; o <<= 1) {
            int v = __shfl_up(inc, o);
            if (tid >= o) inc += v;
        }
        off_l[tid] = inc - dd;
        int rank = 0;
        #pragma unroll
        for (int j = 0; j < 32; j++) {
            int dj = __shfl(dd, j);
            rank += (dj > dd) || (dj == dd && j < tid);
        }
        perm_s[rank] = (u8)tid;      // rank 0 = highest degree
    }
    __syncthreads();

    // ---- counting-sort placement ----
    #pragma unroll
    for (int i = 0; i < 6; i++) {
        u32 v = ve[i];
        if ((int)(v >> 22) == quarter) {
            int lnn = (v >> 17) & 31;
            int p = off_l[lnn] + atomicAdd(&cur_l[lnn], 1);
            if (p < SCAP) sorted_s[p] = (int)(v & 0x1FFFFu);
        }
    }
    __syncthreads();

    // ---- gather: 4 waves x 8 nodes (degree-sorted), FLAT unroll-8 ----
    int nl8 = lane >> 3;             // node-slot within wave
    int c = lane & 7;                // feature octet
    int nl = perm_s[wv * 8 + nl8];   // physical local node (broadcast read)
    int n = nbase + nl;
    int d = deg_l[nl];
    int st = off_l[nl];

    int maxd = d;
    maxd = max(maxd, __shfl_xor(maxd, 8));
    maxd = max(maxd, __shfl_xor(maxd, 16));
    maxd = max(maxd, __shfl_xor(maxd, 32));

    float acc[8];
    #pragma unroll
    for (int j = 0; j < 8; j++) acc[j] = 0.0f;

    int dm1 = (d > 0) ? (d - 1) : 0;
    int sb = (d > 0) ? st : 0;
    for (int k = 0; k < maxd; k += 8) {
        int ix[8];
        #pragma unroll
        for (int u = 0; u < 8; u++) ix[u] = sb + min(k + u, dm1);
        int s0 = sorted_s[ix[0]];
        int s1 = sorted_s[ix[1]];
        int s2 = sorted_s[ix[2]];
        int s3 = sorted_s[ix[3]];
        int s4 = sorted_s[ix[4]];
        int s5 = sorted_s[ix[5]];
        int s6 = sorted_s[ix[6]];
        int s7 = sorted_s[ix[7]];
        bf16x8 r0 = *(const bf16x8*)&xb[(size_t)s0 * D + c * 8];
        bf16x8 r1 = *(const bf16x8*)&xb[(size_t)s1 * D + c * 8];
        bf16x8 r2 = *(const bf16x8*)&xb[(size_t)s2 * D + c * 8];
        bf16x8 r3 = *(const bf16x8*)&xb[(size_t)s3 * D + c * 8];
        bf16x8 r4 = *(const bf16x8*)&xb[(size_t)s4 * D + c * 8];
        bf16x8 r5 = *(const bf16x8*)&xb[(size_t)s5 * D + c * 8];
        bf16x8 r6 = *(const bf16x8*)&xb[(size_t)s6 * D + c * 8];
        bf16x8 r7 = *(const bf16x8*)&xb[(size_t)s7 * D + c * 8];
        float m0 = (k + 0 < d) ? 1.0f : 0.0f;
        float m1 = (k + 1 < d) ? 1.0f : 0.0f;
        float m2 = (k + 2 < d) ? 1.0f : 0.0f;
        float m3 = (k + 3 < d) ? 1.0f : 0.0f;
        float m4 = (k + 4 < d) ? 1.0f : 0.0f;
        float m5 = (k + 5 < d) ? 1.0f : 0.0f;
        float m6 = (k + 6 < d) ? 1.0f : 0.0f;
        float m7 = (k + 7 < d) ? 1.0f : 0.0f;
        #pragma unroll
        for (int j = 0; j < 8; j++) acc[j] = fmaf(m0, bf2f((u16)r0[j]), acc[j]);
        #pragma unroll
        for (int j = 0; j < 8; j++) acc[j] = fmaf(m1, bf2f((u16)r1[j]), acc[j]);
        #pragma unroll
        for (int j = 0; j < 8; j++) acc[j] = fmaf(m2, bf2f((u16)r2[j]), acc[j]);
        #pragma unroll
        for (int j = 0; j < 8; j++) acc[j] = fmaf(m3, bf2f((u16)r3[j]), acc[j]);
        #pragma unroll
        for (int j = 0; j < 8; j++) acc[j] = fmaf(m4, bf2f((u16)r4[j]), acc[j]);
        #pragma unroll
        for (int j = 0; j < 8; j++) acc[j] = fmaf(m5, bf2f((u16)r5[j]), acc[j]);
        #pragma unroll
        for (int j = 0; j < 8; j++) acc[j] = fmaf(m6, bf2f((u16)r6[j]), acc[j]);
        #pragma unroll
        for (int j = 0; j < 8; j++) acc[j] = fmaf(m7, bf2f((u16)r7[j]), acc[j]);
    }

    // ---- epilogue coords (needed for B-frag addresses) ----
    int mtile = wv >> 1;             // 0..1 -> 16-row tile of 32
    int nt0 = (wv & 1) * 2;          // col tiles {0,1} or {2,3}
    int lrow = lane & 15;
    int quad = lane >> 4;

    // issue B-fragment loads from Wb (bf16 [64][128], L2-hot) — latency
    // hides under As writes + barrier; gather buffers are dead here.
    const u16* wb0 = &Wb[((nt0 + 0) * 16 + lrow) * 128 + quad * 8];
    const u16* wb1 = &Wb[((nt0 + 1) * 16 + lrow) * 128 + quad * 8];
    bf16x8 bf0_0 = *(const bf16x8*)&wb0[0 * 32];
    bf16x8 bf0_1 = *(const bf16x8*)&wb0[1 * 32];
    bf16x8 bf0_2 = *(const bf16x8*)&wb0[2 * 32];
    bf16x8 bf0_3 = *(const bf16x8*)&wb0[3 * 32];
    bf16x8 bf1_0 = *(const bf16x8*)&wb1[0 * 32];
    bf16x8 bf1_1 = *(const bf16x8*)&wb1[1 * 32];
    bf16x8 bf1_2 = *(const bf16x8*)&wb1[2 * 32];
    bf16x8 bf1_3 = *(const bf16x8*)&wb1[3 * 32];

    float inv = (d > 0) ? (1.0f / (float)d) : 0.0f;
    bf16x8 p;
    #pragma unroll
    for (int j = 0; j < 8; j++) p[j] = (short)f2bf(acc[j] * inv);
    *(bf16x8*)&As[nl * STR + c * 8] = p;      // perm is a bijection: all 32 rows written
    bf16x8 xr = {0, 0, 0, 0, 0, 0, 0, 0};
    if (n < N_NODES) xr = *(const bf16x8*)&xb[(size_t)n * D + c * 8];
    *(bf16x8*)&As[nl * STR + 64 + c * 8] = xr;
    __syncthreads();

    // ---- MFMA epilogue (C/D col=lane&15, row=quad*4+reg; m89/m91) ----
    const u16* Ab = &As[(mtile * 16 + lrow) * STR + quad * 8];

    float bias0 = bl[(nt0 + 0) * 16 + lrow];
    float bias1 = bl[(nt0 + 1) * 16 + lrow];
    f32x4 acc0 = {bias0, bias0, bias0, bias0};
    f32x4 acc1 = {bias1, bias1, bias1, bias1};

    {
        bf16x8 af;
        af = *(const bf16x8*)&Ab[0 * 32];
        acc0 = __builtin_amdgcn_mfma_f32_16x16x32_bf16(af, bf0_0, acc0, 0, 0, 0);
        acc1 = __builtin_amdgcn_mfma_f32_16x16x32_bf16(af, bf1_0, acc1, 0, 0, 0);
        af = *(const bf16x8*)&Ab[1 * 32];
        acc0 = __builtin_amdgcn_mfma_f32_16x16x32_bf16(af, bf0_1, acc0, 0, 0, 0);
        acc1 = __builtin_amdgcn_mfma_f32_16x16x32_bf16(af, bf1_1, acc1, 0, 0, 0);
        af = *(const bf16x8*)&Ab[2 * 32];
        acc0 = __builtin_amdgcn_mfma_f32_16x16x32_bf16(af, bf0_2, acc0, 0, 0, 0);
        acc1 = __builtin_amdgcn_mfma_f32_16x16x32_bf16(af, bf1_2, acc1, 0, 0, 0);
        af = *(const bf16x8*)&Ab[3 * 32];
        acc0 = __builtin_amdgcn_mfma_f32_16x16x32_bf16(af, bf0_3, acc0, 0, 0, 0);
        acc1 = __builtin_amdgcn_mfma_f32_16x16x32_bf16(af, bf1_3, acc1, 0, 0, 0);
    }

    int node = nbase + mtile * 16 + quad * 4;
    #pragma unroll
    for (int r = 0; r < 4; r++) {
        if (node + r < N_NODES) {
            out[(size_t)(node + r) * D + (nt0 + 0) * 16 + lrow] = fmaxf(acc0[r], 0.0f);
            out[(size_t)(node + r) * D + (nt0 + 1) * 16 + lrow] = fmaxf(acc1[r], 0.0f);
        }
    }
}

extern "C" void kernel_launch(void* const* d_in, const int* in_sizes, int n_in,
                              void* d_out, int out_size, void* d_ws, size_t ws_size,
                              hipStream_t stream) {
    const float* x  = (const float*)d_in[0];
    const int*   ei = (const int*)d_in[1];
    const float* Wl = (const float*)d_in[2];
    const float* bl = (const float*)d_in[3];
    const float* Wr = (const float*)d_in[4];
    float* out = (float*)d_out;

    // ws: cur2[1024 ints = 4 KB] | Wb[8192 u16 = 16 KB] |
    //     pairs2[NFINE*CAP2 u32 = 4.8 MB] | xb[12.8 MB]
    char* p = (char*)d_ws;
    int* cur2   = (int*)p;                        p += 1024 * sizeof(int);
    u16* Wb     = (u16*)p;                        p += 8192 * sizeof(u16);
    u32* pairs2 = (u32*)p;                        p += (size_t)NFINE * CAP2 * sizeof(u32);
    u16* xb     = (u16*)p;

    hipMemsetAsync(cur2, 0, 1024 * sizeof(int), stream);
    build5_kernel<<<EDGE_BLOCKS, 1024, 0, stream>>>(x, xb, Wl, Wr, Wb, ei, cur2, pairs2);
    cons8_kernel<<<CONS_BLOCKS, 256, 0, stream>>>(xb, Wb, bl, cur2, pairs2, out);
}

// Round 12
// 126.939 us; speedup vs baseline: 1.0205x; 1.0205x over previous
//
#include <hip/hip_runtime.h>

#define N_NODES 100000
#define N_EDGES 1000000
#define D 64

#define NFINE 782             // fine bin = dst >> 7 (128 nodes each)
#define CAP2 1536             // per-bin cap: mean 1280 + ~7 sigma
#define CHUNK 4096            // edges per build block (R2/R5-measured best)
#define EDGE_BLOCKS 245       // ceil(1e6 / 4096)
#define CONV_ITEMS 1600000    // N*D/4 float4s
#define CONV_STRIDE (EDGE_BLOCKS * 1024)
#define CONS_BLOCKS 3128      // 782 bins x 4 quarters, 32 nodes / 256-thr block
#define STR 132               // As row stride in u16
#define SCAP 512              // sorted_s slots per 32-node quarter

typedef unsigned short u16;
typedef unsigned int u32;
using bf16x8 = __attribute__((ext_vector_type(8))) short;
using f32x4  = __attribute__((ext_vector_type(4))) float;

__device__ __forceinline__ u16 f2bf(float f) {   // RNE float->bf16
    u32 u = __float_as_uint(f);
    return (u16)((u + 0x7FFF + ((u >> 16) & 1)) >> 16);
}
__device__ __forceinline__ float bf2f(u16 v) {
    return __uint_as_float(((u32)v) << 16);
}

// ===========================================================================
// build5: R10 verbatim (128.1us best) — build + conv fused (fusion isolated
// at -1.4us), plain cur2 (CSTR padding isolated at +5.4us), LDS counting
// sort CHUNK 4096 (scatter +7us, CHUNK 2048 +5us). Block 0 pre-converts
// weights into Wb. cur2 zeroed by hipMemsetAsync.
// Packed pair = src(17b) | dst_local7 << 17.
// ===========================================================================
__global__ __launch_bounds__(1024) void build5_kernel(
    const float* __restrict__ x, u16* __restrict__ xb,
    const float* __restrict__ Wl, const float* __restrict__ Wr,
    u16* __restrict__ Wb,
    const int* __restrict__ ei, int* __restrict__ cur2,
    u32* __restrict__ pairs2) {
    __shared__ u32 sorted[CHUNK];    // 16 KB
    __shared__ u16 binof[CHUNK];     //  8 KB
    __shared__ int hist[NFINE];
    __shared__ int off_l[NFINE];
    __shared__ int cur_l[NFINE];
    __shared__ int base_g[NFINE];
    __shared__ int wsum[16];

    int b = blockIdx.x;
    int t = threadIdx.x;
    int ln = t & 63;
    int wv = t >> 6;

    // int64/int32 detect: indices < 2^17 -> int64 odd u32 words all zero
    const u32* uu = (const u32*)ei;
    int f = 1;
    #pragma unroll
    for (int i = 1; i < 16; i += 2)
        if (uu[i] != 0u) f = 0;

    if (t < NFINE) hist[t] = 0;
    __syncthreads();

    int e0 = b * CHUNK;
    int e1 = min(e0 + CHUNK, N_EDGES);
    int ne = e1 - e0;

    // ---- edge loads (coalesced uint2 for int64 path) ----
    const uint2* e64 = (const uint2*)ei;
    int srcv[4], dstv[4];
    #pragma unroll
    for (int i = 0; i < 4; i++) {
        int ee = e0 + t + i * 1024;
        bool ok = ee < e1;
        if (f) {
            uint2 sv = ok ? e64[ee] : make_uint2(0u, 0u);
            uint2 dv = ok ? e64[N_EDGES + ee] : make_uint2(0u, 0u);
            srcv[i] = (int)sv.x;
            dstv[i] = ok ? (int)dv.x : -1;
        } else {
            srcv[i] = ok ? ei[ee] : 0;
            dstv[i] = ok ? ei[N_EDGES + ee] : -1;
        }
    }

    // ---- issue conv-slice loads early (7 float4/thread, grid-stride) ----
    float4 cf[7];
    const float4* x4 = (const float4*)x;
    #pragma unroll
    for (int j = 0; j < 7; j++) {
        int i = b * 1024 + t + j * CONV_STRIDE;
        cf[j] = (i < CONV_ITEMS) ? x4[i] : make_float4(0.f, 0.f, 0.f, 0.f);
    }

    // ---- block 0: pre-convert weights into Wb bf16 [64][128] ----
    if (b == 0 && t < 256) {
        int o = t >> 2;
        int k0 = (t & 3) * 32;
        const float4* wlf = (const float4*)Wl;
        const float4* wrf = (const float4*)Wr;
        #pragma unroll
        for (int j = 0; j < 8; j++) {
            int k = k0 + j * 4;
            float4 v = (k < 64) ? wlf[(o * 64 + k) >> 2]
                                : wrf[(o * 64 + k - 64) >> 2];
            *(ushort4*)&Wb[o * 128 + k] =
                make_ushort4(f2bf(v.x), f2bf(v.y), f2bf(v.z), f2bf(v.w));
        }
    }

    // ---- histogram ----
    #pragma unroll
    for (int i = 0; i < 4; i++)
        if (dstv[i] >= 0) atomicAdd(&hist[dstv[i] >> 7], 1);
    __syncthreads();

    // ---- two-level wave scan over 782 bins ----
    int h = (t < NFINE) ? hist[t] : 0;
    int inc = h;
    #pragma unroll
    for (int o = 1; o < 64; o <<= 1) {
        int v = __shfl_up(inc, o);
        if (ln >= o) inc += v;
    }
    if (ln == 63) wsum[wv] = inc;
    __syncthreads();
    if (t < 16) {
        int w = wsum[t];
        int winc = w;
        #pragma unroll
        for (int o = 1; o < 16; o <<= 1) {
            int v = __shfl_up(winc, o);
            if (t >= o) winc += v;
        }
        wsum[t] = winc - w;          // exclusive wave offset
    }
    __syncthreads();

    // ---- reservation (plain cur2 — same-line L2 atomic batching helps) ----
    if (t < NFINE) {
        int ex = inc - h + wsum[wv]; // exclusive prefix
        off_l[t] = ex;
        cur_l[t] = ex;
        base_g[t] = h ? atomicAdd(&cur2[t], h) : 0;
    }

    // ---- conv convert + store (overlaps reservation atomic latency) ----
    #pragma unroll
    for (int j = 0; j < 7; j++) {
        int i = b * 1024 + t + j * CONV_STRIDE;
        if (i < CONV_ITEMS) {
            float4 v = cf[j];
            ((ushort4*)xb)[i] =
                make_ushort4(f2bf(v.x), f2bf(v.y), f2bf(v.z), f2bf(v.w));
        }
    }
    __syncthreads();

    // ---- placement: counting-sort into LDS ----
    #pragma unroll
    for (int i = 0; i < 4; i++) {
        if (dstv[i] >= 0) {
            int fine = dstv[i] >> 7;
            int slot = atomicAdd(&cur_l[fine], 1);
            sorted[slot] = (u32)srcv[i] | ((u32)(dstv[i] & 127) << 17);
            binof[slot] = (u16)fine;
        }
    }
    __syncthreads();

    // ---- linear coalesced flush ----
    for (int i = t; i < ne; i += 1024) {
        int fine = binof[i];
        int pos = base_g[fine] + (i - off_l[fine]);
        if (pos < CAP2)
            pairs2[(size_t)fine * CAP2 + pos] = sorted[i];
    }
}

// ===========================================================================
// cons7b: R10 verbatim (128.1us best). R11 isolated degree-sorted
// node->wave assignment at +1.4us (gather trip-count is NOT on the
// critical path — fully latency-bound; and the perm scatters the
// self-row loads/As writes, losing 128B-per-group coalescing). Reverted.
// grid 3128, block 256 (4 waves), 32 nodes/block; no Bs LDS (weights
// from Wb into regs); flat unroll-8 gather (8 loads in flight/lane);
// __launch_bounds__(256,8) (isolated -1.3us).
// MFMA epilogue: C/D col=lane&15, row=quad*4+reg (m89/m91).
// ===========================================================================
__global__ __launch_bounds__(256, 8) void cons7_kernel(
    const u16* __restrict__ xb, const u16* __restrict__ Wb,
    const float* __restrict__ bl,
    const int* __restrict__ cur2, const u32* __restrict__ pairs2,
    float* __restrict__ out) {
    __shared__ u16 As[32 * STR];     //  8448 B
    __shared__ int sorted_s[SCAP];   //  2048 B
    __shared__ int deg_l[32];
    __shared__ int off_l[32];
    __shared__ int cur_l[32];

    int tid = threadIdx.x;
    int bin = blockIdx.x >> 2;
    int quarter = blockIdx.x & 3;
    int nbase = bin * 128 + quarter * 32;
    if (nbase >= N_NODES) return;    // phantom quarters of last bin

    int lane = tid & 63;
    int wv = tid >> 6;

    // ---- issue pair loads first (long-latency, hide under init) ----
    int cnt = min(cur2[bin], CAP2);
    const u32* pb = &pairs2[(size_t)bin * CAP2];
    u32 ve[6];                       // CAP2/256 == 6
    #pragma unroll
    for (int i = 0; i < 6; i++) {
        int e = tid + i * 256;
        ve[i] = (e < cnt) ? pb[e] : 0xFFFFFFFFu;   // sentinel fails quarter test
    }

    if (tid < 32) { deg_l[tid] = 0; cur_l[tid] = 0; }
    if (tid == 0) sorted_s[0] = 0;   // safe slot for d==0 lanes
    __syncthreads();

    // ---- histogram over this quarter's 32 local nodes ----
    #pragma unroll
    for (int i = 0; i < 6; i++) {
        u32 v = ve[i];
        if ((int)(v >> 22) == quarter) atomicAdd(&deg_l[(v >> 17) & 31], 1);
    }
    __syncthreads();

    // ---- exclusive scan of 32 degrees (lanes 0..31 of wave 0) ----
    if (tid < 32) {
        int dd = deg_l[tid];
        int inc = dd;
        #pragma unroll
        for (int o = 1; o < 32; o <<= 1) {
            int v = __shfl_up(inc, o);
            if (tid >= o) inc += v;
        }
        off_l[tid] = inc - dd;
    }
    __syncthreads();

    // ---- counting-sort placement ----
    #pragma unroll
    for (int i = 0; i < 6; i++) {
        u32 v = ve[i];
        if ((int)(v >> 22) == quarter) {
            int lnn = (v >> 17) & 31;
            int p = off_l[lnn] + atomicAdd(&cur_l[lnn], 1);
            if (p < SCAP) sorted_s[p] = (int)(v & 0x1FFFFu);
        }
    }
    __syncthreads();

    // ---- gather: 4 waves x 8 nodes, FLAT unroll-8 (8 loads in flight) ----
    int nl8 = lane >> 3;             // node within wave
    int c = lane & 7;                // feature octet
    int nl = wv * 8 + nl8;           // local node 0..31
    int n = nbase + nl;
    int d = deg_l[nl];
    int st = off_l[nl];

    int maxd = d;
    maxd = max(maxd, __shfl_xor(maxd, 8));
    maxd = max(maxd, __shfl_xor(maxd, 16));
    maxd = max(maxd, __shfl_xor(maxd, 32));

    float acc[8];
    #pragma unroll
    for (int j = 0; j < 8; j++) acc[j] = 0.0f;

    int dm1 = (d > 0) ? (d - 1) : 0;
    int sb = (d > 0) ? st : 0;
    for (int k = 0; k < maxd; k += 8) {
        int ix[8];
        #pragma unroll
        for (int u = 0; u < 8; u++) ix[u] = sb + min(k + u, dm1);
        int s0 = sorted_s[ix[0]];
        int s1 = sorted_s[ix[1]];
        int s2 = sorted_s[ix[2]];
        int s3 = sorted_s[ix[3]];
        int s4 = sorted_s[ix[4]];
        int s5 = sorted_s[ix[5]];
        int s6 = sorted_s[ix[6]];
        int s7 = sorted_s[ix[7]];
        bf16x8 r0 = *(const bf16x8*)&xb[(size_t)s0 * D + c * 8];
        bf16x8 r1 = *(const bf16x8*)&xb[(size_t)s1 * D + c * 8];
        bf16x8 r2 = *(const bf16x8*)&xb[(size_t)s2 * D + c * 8];
        bf16x8 r3 = *(const bf16x8*)&xb[(size_t)s3 * D + c * 8];
        bf16x8 r4 = *(const bf16x8*)&xb[(size_t)s4 * D + c * 8];
        bf16x8 r5 = *(const bf16x8*)&xb[(size_t)s5 * D + c * 8];
        bf16x8 r6 = *(const bf16x8*)&xb[(size_t)s6 * D + c * 8];
        bf16x8 r7 = *(const bf16x8*)&xb[(size_t)s7 * D + c * 8];
        float m0 = (k + 0 < d) ? 1.0f : 0.0f;
        float m1 = (k + 1 < d) ? 1.0f : 0.0f;
        float m2 = (k + 2 < d) ? 1.0f : 0.0f;
        float m3 = (k + 3 < d) ? 1.0f : 0.0f;
        float m4 = (k + 4 < d) ? 1.0f : 0.0f;
        float m5 = (k + 5 < d) ? 1.0f : 0.0f;
        float m6 = (k + 6 < d) ? 1.0f : 0.0f;
        float m7 = (k + 7 < d) ? 1.0f : 0.0f;
        #pragma unroll
        for (int j = 0; j < 8; j++) acc[j] = fmaf(m0, bf2f((u16)r0[j]), acc[j]);
        #pragma unroll
        for (int j = 0; j < 8; j++) acc[j] = fmaf(m1, bf2f((u16)r1[j]), acc[j]);
        #pragma unroll
        for (int j = 0; j < 8; j++) acc[j] = fmaf(m2, bf2f((u16)r2[j]), acc[j]);
        #pragma unroll
        for (int j = 0; j < 8; j++) acc[j] = fmaf(m3, bf2f((u16)r3[j]), acc[j]);
        #pragma unroll
        for (int j = 0; j < 8; j++) acc[j] = fmaf(m4, bf2f((u16)r4[j]), acc[j]);
        #pragma unroll
        for (int j = 0; j < 8; j++) acc[j] = fmaf(m5, bf2f((u16)r5[j]), acc[j]);
        #pragma unroll
        for (int j = 0; j < 8; j++) acc[j] = fmaf(m6, bf2f((u16)r6[j]), acc[j]);
        #pragma unroll
        for (int j = 0; j < 8; j++) acc[j] = fmaf(m7, bf2f((u16)r7[j]), acc[j]);
    }

    // ---- epilogue coords (needed for B-frag addresses) ----
    int mtile = wv >> 1;             // 0..1 -> 16-row tile of 32
    int nt0 = (wv & 1) * 2;          // col tiles {0,1} or {2,3}
    int lrow = lane & 15;
    int quad = lane >> 4;

    // issue B-fragment loads from Wb (bf16 [64][128], L2-hot) — latency
    // hides under As writes + barrier; gather buffers are dead here.
    const u16* wb0 = &Wb[((nt0 + 0) * 16 + lrow) * 128 + quad * 8];
    const u16* wb1 = &Wb[((nt0 + 1) * 16 + lrow) * 128 + quad * 8];
    bf16x8 bf0_0 = *(const bf16x8*)&wb0[0 * 32];
    bf16x8 bf0_1 = *(const bf16x8*)&wb0[1 * 32];
    bf16x8 bf0_2 = *(const bf16x8*)&wb0[2 * 32];
    bf16x8 bf0_3 = *(const bf16x8*)&wb0[3 * 32];
    bf16x8 bf1_0 = *(const bf16x8*)&wb1[0 * 32];
    bf16x8 bf1_1 = *(const bf16x8*)&wb1[1 * 32];
    bf16x8 bf1_2 = *(const bf16x8*)&wb1[2 * 32];
    bf16x8 bf1_3 = *(const bf16x8*)&wb1[3 * 32];

    float inv = (d > 0) ? (1.0f / (float)d) : 0.0f;
    bf16x8 p;
    #pragma unroll
    for (int j = 0; j < 8; j++) p[j] = (short)f2bf(acc[j] * inv);
    *(bf16x8*)&As[nl * STR + c * 8] = p;
    bf16x8 xr = {0, 0, 0, 0, 0, 0, 0, 0};
    if (n < N_NODES) xr = *(const bf16x8*)&xb[(size_t)n * D + c * 8];
    *(bf16x8*)&As[nl * STR + 64 + c * 8] = xr;
    __syncthreads();

    // ---- MFMA epilogue (C/D col=lane&15, row=quad*4+reg; m89/m91) ----
    const u16* Ab = &As[(mtile * 16 + lrow) * STR + quad * 8];

    float bias0 = bl[(nt0 + 0) * 16 + lrow];
    float bias1 = bl[(nt0 + 1) * 16 + lrow];
    f32x4 acc0 = {bias0, bias0, bias0, bias0};
    f32x4 acc1 = {bias1, bias1, bias1, bias1};

    {
        bf16x8 af;
        af = *(const bf16x8*)&Ab[0 * 32];
        acc0 = __builtin_amdgcn_mfma_f32_16x16x32_bf16(af, bf0_0, acc0, 0, 0, 0);
        acc1 = __builtin_amdgcn_mfma_f32_16x16x32_bf16(af, bf1_0, acc1, 0, 0, 0);
        af = *(const bf16x8*)&Ab[1 * 32];
        acc0 = __builtin_amdgcn_mfma_f32_16x16x32_bf16(af, bf0_1, acc0, 0, 0, 0);
        acc1 = __builtin_amdgcn_mfma_f32_16x16x32_bf16(af, bf1_1, acc1, 0, 0, 0);
        af = *(const bf16x8*)&Ab[2 * 32];
        acc0 = __builtin_amdgcn_mfma_f32_16x16x32_bf16(af, bf0_2, acc0, 0, 0, 0);
        acc1 = __builtin_amdgcn_mfma_f32_16x16x32_bf16(af, bf1_2, acc1, 0, 0, 0);
        af = *(const bf16x8*)&Ab[3 * 32];
        acc0 = __builtin_amdgcn_mfma_f32_16x16x32_bf16(af, bf0_3, acc0, 0, 0, 0);
        acc1 = __builtin_amdgcn_mfma_f32_16x16x32_bf16(af, bf1_3, acc1, 0, 0, 0);
    }

    int node = nbase + mtile * 16 + quad * 4;
    #pragma unroll
    for (int r = 0; r < 4; r++) {
        if (node + r < N_NODES) {
            out[(size_t)(node + r) * D + (nt0 + 0) * 16 + lrow] = fmaxf(acc0[r], 0.0f);
            out[(size_t)(node + r) * D + (nt0 + 1) * 16 + lrow] = fmaxf(acc1[r], 0.0f);
        }
    }
}

extern "C" void kernel_launch(void* const* d_in, const int* in_sizes, int n_in,
                              void* d_out, int out_size, void* d_ws, size_t ws_size,
                              hipStream_t stream) {
    const float* x  = (const float*)d_in[0];
    const int*   ei = (const int*)d_in[1];
    const float* Wl = (const float*)d_in[2];
    const float* bl = (const float*)d_in[3];
    const float* Wr = (const float*)d_in[4];
    float* out = (float*)d_out;

    // ws: cur2[1024 ints = 4 KB] | Wb[8192 u16 = 16 KB] |
    //     pairs2[NFINE*CAP2 u32 = 4.8 MB] | xb[12.8 MB]
    char* p = (char*)d_ws;
    int* cur2   = (int*)p;                        p += 1024 * sizeof(int);
    u16* Wb     = (u16*)p;                        p += 8192 * sizeof(u16);
    u32* pairs2 = (u32*)p;                        p += (size_t)NFINE * CAP2 * sizeof(u32);
    u16* xb     = (u16*)p;

    hipMemsetAsync(cur2, 0, 1024 * sizeof(int), stream);
    build5_kernel<<<EDGE_BLOCKS, 1024, 0, stream>>>(x, xb, Wl, Wr, Wb, ei, cur2, pairs2);
    cons7_kernel<<<CONS_BLOCKS, 256, 0, stream>>>(xb, Wb, bl, cur2, pairs2, out);
}